// Round 14
// baseline (333.434 us; speedup 1.0000x reference)
//
#include <hip/hip_runtime.h>
#include <math.h>

#define N_SEQ 20000
#define LCH 64
#define NCH 313   // ceil(20000/64)
#define NB7 79    // ceil(20000/256)
#define PF 16     // k5 prefetch depth

#define DOT4(a,b) ((a).x*(b).x + (a).y*(b).y + (a).z*(b).z + (a).w*(b).w)

typedef __attribute__((ext_vector_type(8))) short short8b;   // 8 bf16 (4 VGPR)
typedef __attribute__((ext_vector_type(4))) float f32x4;

__device__ __forceinline__ float siluf(float v) { return v / (1.f + __expf(-v)); }

__device__ __forceinline__ ushort bf16rne(float f) {
  uint u = __float_as_uint(f);
  return (ushort)((u + 0x7fffu + ((u >> 16) & 1u)) >> 16);
}
__device__ __forceinline__ float bf2f(ushort h) { return __uint_as_float(((uint)h) << 16); }

// K0: one-time W1 f32 -> bf16 hi/lo planes (64x1024)
__global__ __launch_bounds__(256) void k0_convW(
    const float* __restrict__ W1, ushort* __restrict__ whi, ushort* __restrict__ wlo)
{
  int i = blockIdx.x * 256 + threadIdx.x;   // 65536 elems
  float v = W1[i];
  ushort h = bf16rne(v);
  whi[i] = h;
  wlo[i] = bf16rne(v - bf2f(h));
}

// K1: feature = relu(x_path @ W1.T + b1), fused bf16-split MFMA.
// 32-row tiles (grid 625 exact), 512 threads = 8 waves.
// 4-deep STATIC prefetch ring (slots s0..s3): issue chunk p+4, compute buf[p&1],
// write chunk p+1 -> buf[(p+1)&1]. vmcnt-wait distance = 3 phases.
__global__ __launch_bounds__(512) void k1_fused(
    const float* __restrict__ xp, const ushort* __restrict__ whi,
    const ushort* __restrict__ wlo, const float* __restrict__ b1,
    float* __restrict__ feat)
{
  __shared__ ushort a_hi[2][32 * 40];
  __shared__ ushort a_lo[2][32 * 40];
  __shared__ ushort b_hi[2][64 * 40];
  __shared__ ushort b_lo[2][64 * 40];
  const int tid = threadIdx.x;
  const int rb = blockIdx.x * 32;
  const int wv = tid >> 6, lane = tid & 63;
  const int i16 = lane & 15, kb = lane >> 4;
  const int rt = (wv >> 2) * 16;
  const int ct = (wv & 3) * 16;
  const bool isA = tid < 256;          // waves 0-3 stage A, waves 4-7 stage B
  const int asrow = tid >> 3;          // 0..31
  const int askq = (tid & 7) * 4;      // k offset (f32 lanes)
  const int bsid = tid - 256;
  const int brow = bsid >> 2;          // 0..63
  const int bkq = (bsid & 3) * 8;      // k offset (ushort lanes)

  float4 ar0, ar1, ar2, ar3;
  uint4 bh0, bh1, bh2, bh3, bl0, bl1, bl2, bl3;

  auto issue = [&](int ks, float4& ar, uint4& bh, uint4& bl) {
    const int k0 = ks * 32;
    if (isA) {
      ar = *(const float4*)&xp[(size_t)(rb + asrow) * 1024 + k0 + askq];
    } else {
      size_t off = (size_t)brow * 1024 + k0 + bkq;
      bh = *(const uint4*)&whi[off];
      bl = *(const uint4*)&wlo[off];
    }
  };
  auto writeb = [&](const float4& ar, const uint4& bh, const uint4& bl, int buf) {
    if (isA) {
      ushort4 h, l;
      h.x = bf16rne(ar.x); l.x = bf16rne(ar.x - bf2f(h.x));
      h.y = bf16rne(ar.y); l.y = bf16rne(ar.y - bf2f(h.y));
      h.z = bf16rne(ar.z); l.z = bf16rne(ar.z - bf2f(h.z));
      h.w = bf16rne(ar.w); l.w = bf16rne(ar.w - bf2f(h.w));
      *(ushort4*)&a_hi[buf][asrow * 40 + askq] = h;
      *(ushort4*)&a_lo[buf][asrow * 40 + askq] = l;
    } else {
      *(uint4*)&b_hi[buf][brow * 40 + bkq] = bh;
      *(uint4*)&b_lo[buf][brow * 40 + bkq] = bl;
    }
  };
  const int koff = kb * 8;
  f32x4 acc = (f32x4){0.f, 0.f, 0.f, 0.f};

#define K1_MFMA(CBUF) { \
    short8b ahf = *(const short8b*)&a_hi[CBUF][(rt + i16) * 40 + koff]; \
    short8b alf = *(const short8b*)&a_lo[CBUF][(rt + i16) * 40 + koff]; \
    short8b bhf = *(const short8b*)&b_hi[CBUF][(ct + i16) * 40 + koff]; \
    short8b blf = *(const short8b*)&b_lo[CBUF][(ct + i16) * 40 + koff]; \
    acc = __builtin_amdgcn_mfma_f32_16x16x32_bf16(ahf, bhf, acc, 0, 0, 0); \
    acc = __builtin_amdgcn_mfma_f32_16x16x32_bf16(ahf, blf, acc, 0, 0, 0); \
    acc = __builtin_amdgcn_mfma_f32_16x16x32_bf16(alf, bhf, acc, 0, 0, 0); \
  }
#define K1_PHASE(P, AI, BHI, BLI, AW, BHW, BLW, CBUF, WBUF) \
  if ((P) + 4 < 32) issue((P) + 4, AI, BHI, BLI); \
  K1_MFMA(CBUF) \
  if ((P) + 1 < 32) writeb(AW, BHW, BLW, WBUF); \
  __syncthreads();

  issue(0, ar0, bh0, bl0);
  issue(1, ar1, bh1, bl1);
  issue(2, ar2, bh2, bl2);
  issue(3, ar3, bh3, bl3);
  writeb(ar0, bh0, bl0, 0);
  __syncthreads();
  for (int t = 0; t < 32; t += 4) {
    K1_PHASE(t + 0, ar0, bh0, bl0, ar1, bh1, bl1, 0, 1)
    K1_PHASE(t + 1, ar1, bh1, bl1, ar2, bh2, bl2, 1, 0)
    K1_PHASE(t + 2, ar2, bh2, bl2, ar3, bh3, bl3, 0, 1)
    K1_PHASE(t + 3, ar3, bh3, bl3, ar0, bh0, bl0, 1, 0)
  }
#undef K1_PHASE
#undef K1_MFMA
  // D: row = rt + kb*4 + r, col = ct + i16 ; 625*32 = 20000 exact, no bounds
  const int col = ct + i16;
  const float bb = b1[col];
  #pragma unroll
  for (int r = 0; r < 4; r++) {
    int n = rb + rt + kb * 4 + r;
    feat[n * 64 + col] = fmaxf(acc[r] + bb, 0.f);
  }
}

// K2: xz = feature @ in_proj_w.T ; split -> xz_x (raw), zs = silu(z)
// grid 313: feature tile staged ONCE, loop 4 column tiles (wl re-staged per 32-k chunk)
__global__ __launch_bounds__(256) void k2_inproj(
    const float* __restrict__ featg, const float* __restrict__ ipw,
    float* __restrict__ xz_x, float* __restrict__ zs)
{
  __shared__ float fs[64 * 68];   // [k][row]
  __shared__ float wl[32 * 68];   // [k][col]
  const int tid = threadIdx.x;
  const int rb = blockIdx.x * 64;
  // stage feature tile: 64 rows x 64 k (float4 loads, transposed scatter)
  #pragma unroll
  for (int i = 0; i < 4; i++) {
    int idx = tid + i * 256;        // 0..1023
    int r = idx >> 4, k4 = idx & 15;
    int n = rb + r;
    float4 v = {0, 0, 0, 0};
    if (n < N_SEQ) v = *(const float4*)&featg[n * 64 + k4 * 4];
    fs[(k4 * 4 + 0) * 68 + r] = v.x;
    fs[(k4 * 4 + 1) * 68 + r] = v.y;
    fs[(k4 * 4 + 2) * 68 + r] = v.z;
    fs[(k4 * 4 + 3) * 68 + r] = v.w;
  }
  const int tr = tid >> 4, tc = tid & 15;
  for (int cb = 0; cb < 4; cb++) {
    float acc[4][4] = {};
    for (int k0 = 0; k0 < 64; k0 += 32) {
      #pragma unroll
      for (int i = 0; i < 8; i++) {
        int idx = tid + i * 256;
        int c = idx >> 5, k = idx & 31;
        wl[k * 68 + c] = ipw[(cb * 64 + c) * 64 + k0 + k];
      }
      __syncthreads();   // covers fs writes on first pass, wl each pass
      #pragma unroll
      for (int k = 0; k < 32; k++) {
        float4 xv = *(const float4*)&fs[(k0 + k) * 68 + tr * 4];
        float4 wv = *(const float4*)&wl[k * 68 + tc * 4];
        acc[0][0] += xv.x*wv.x; acc[0][1] += xv.x*wv.y; acc[0][2] += xv.x*wv.z; acc[0][3] += xv.x*wv.w;
        acc[1][0] += xv.y*wv.x; acc[1][1] += xv.y*wv.y; acc[1][2] += xv.y*wv.z; acc[1][3] += xv.y*wv.w;
        acc[2][0] += xv.z*wv.x; acc[2][1] += xv.z*wv.y; acc[2][2] += xv.z*wv.z; acc[2][3] += xv.z*wv.w;
        acc[3][0] += xv.w*wv.x; acc[3][1] += xv.w*wv.y; acc[3][2] += xv.w*wv.z; acc[3][3] += xv.w*wv.w;
      }
      __syncthreads();
    }
    const int cc = cb * 64 + tc * 4;
    #pragma unroll
    for (int i = 0; i < 4; i++) {
      int n = rb + tr * 4 + i;
      if (n < N_SEQ) {
        if (cc < 128) {
          float4 o = {acc[i][0], acc[i][1], acc[i][2], acc[i][3]};
          *(float4*)&xz_x[n * 128 + cc] = o;
        } else {
          float4 o = {siluf(acc[i][0]), siluf(acc[i][1]), siluf(acc[i][2]), siluf(acc[i][3])};
          *(float4*)&zs[n * 128 + cc - 128] = o;
        }
      }
    }
  }
}

// K3: causal depthwise conv + silu -> xc ; x_dbl = xc @ x_proj_w.T -> dt_raw,B,C ;
//     dt = softplus(dt_raw @ dt_proj_w.T + dt_proj_b)   [512 threads]
__global__ __launch_bounds__(512) void k3_conv_proj(
    const float* __restrict__ xz_x, const float* __restrict__ cw,
    const float* __restrict__ cb, const float* __restrict__ xpw,
    const float* __restrict__ dtw, const float* __restrict__ dtb,
    float* __restrict__ xc, float* __restrict__ dt,
    float* __restrict__ Bm, float* __restrict__ Cm)
{
  __shared__ float xzl[51 * 128];
  __shared__ float xcl[48 * 128];
  __shared__ float xwl[36 * 132];
  __shared__ float dtrl[48 * 4];
  const int tid = threadIdx.x;
  const int r0 = blockIdx.x * 48;
  for (int idx = tid; idx < 51 * 128; idx += 512) {
    int rg = r0 - 3 + (idx >> 7);
    int c = idx & 127;
    xzl[idx] = (rg >= 0 && rg < N_SEQ) ? xz_x[rg * 128 + c] : 0.f;
  }
  for (int idx = tid; idx < 36 * 128; idx += 512) {
    int j = idx >> 7, c = idx & 127;
    xwl[j * 132 + c] = xpw[idx];
  }
  __syncthreads();
  const int c = tid & 127;
  const int rbase = tid >> 7;  // 0..3
  const float4 cw4 = *(const float4*)&cw[c * 4];
  const float cbv = cb[c];
  #pragma unroll
  for (int i = 0; i < 12; i++) {
    int rl = rbase + 4 * i;
    float v = cw4.x * xzl[(rl+0)*128 + c] + cw4.y * xzl[(rl+1)*128 + c]
            + cw4.z * xzl[(rl+2)*128 + c] + cw4.w * xzl[(rl+3)*128 + c] + cbv;
    v = siluf(v);
    xcl[rl * 128 + c] = v;
    int n = r0 + rl;
    if (n < N_SEQ) xc[n * 128 + c] = v;
  }
  __syncthreads();
  for (int idx = tid; idx < 48 * 36; idx += 512) {
    int r = idx / 36, j = idx - r * 36;
    float s = 0.f;
    #pragma unroll
    for (int k = 0; k < 128; k += 4) {
      float4 a = *(const float4*)&xcl[r * 128 + k];
      float4 b = *(const float4*)&xwl[j * 132 + k];
      s += DOT4(a, b);
    }
    int n = r0 + r;
    if (j < 4) dtrl[r * 4 + j] = s;
    else if (n < N_SEQ) {
      if (j < 20) Bm[n * 16 + (j - 4)] = s;
      else        Cm[n * 16 + (j - 20)] = s;
    }
  }
  __syncthreads();
  const float4 dw4 = *(const float4*)&dtw[c * 4];
  const float dbv = dtb[c];
  #pragma unroll
  for (int i = 0; i < 12; i++) {
    int rl = rbase + 4 * i;
    int n = r0 + rl;
    if (n < N_SEQ) {
      float4 dr = *(const float4*)&dtrl[rl * 4];
      float v = DOT4(dr, dw4) + dbv;
      dt[n * 128 + c] = (v > 20.f) ? v : log1pf(__expf(v));
    }
  }
}

// K4 (phase A): per-chunk P and local scan end, LDS chunk-staged (16 rows/chunk, dbuf)
__global__ __launch_bounds__(512) void k4_scanA(
    const float* __restrict__ dt, const float* __restrict__ xc,
    const float* __restrict__ Bm, const float* __restrict__ Alog,
    float* __restrict__ Pb, float* __restrict__ he)
{
  __shared__ float sdt[2][2048];
  __shared__ float sxc[2][2048];
  __shared__ float sB[2][256];
  const int t = threadIdx.x;
  const int chunk = blockIdx.x;
  const int n0 = chunk * LCH;
  const int srow = t >> 5, scol = (t & 31) * 4;
  const int c = t >> 2, sq = t & 3;
  float4 al = *(const float4*)&Alog[t * 4];
  const float A0 = -__expf(al.x), A1 = -__expf(al.y), A2 = -__expf(al.z), A3 = -__expf(al.w);
  float h0=0,h1=0,h2=0,h3=0;
  float p0=1,p1=1,p2=1,p3=1;

  auto stage = [&](int cb, int buf) {
    int n = n0 + cb * 16 + srow;
    float4 vd = {0,0,0,0}, vx = {0,0,0,0};
    if (n < N_SEQ) {
      vd = *(const float4*)&dt[n * 128 + scol];
      vx = *(const float4*)&xc[n * 128 + scol];
    }
    *(float4*)&sdt[buf][srow * 128 + scol] = vd;
    *(float4*)&sxc[buf][srow * 128 + scol] = vx;
    if (t < 64) {
      int br = t >> 2, bq = (t & 3) * 4;
      int nb = n0 + cb * 16 + br;
      float4 vb = {0,0,0,0};
      if (nb < N_SEQ) vb = *(const float4*)&Bm[nb * 16 + bq];
      *(float4*)&sB[buf][br * 16 + bq] = vb;
    }
  };

  stage(0, 0);
  __syncthreads();
  int cur = 0;
  for (int cb = 0; cb < 4; cb++) {
    if (cb + 1 < 4) stage(cb + 1, cur ^ 1);
    #pragma unroll
    for (int rl = 0; rl < 16; rl++) {
      float dtv = sdt[cur][rl * 128 + c];
      float xv  = sxc[cur][rl * 128 + c];
      float4 Bv = *(const float4*)&sB[cur][rl * 16 + sq * 4];
      float bs = dtv * xv;
      float e0 = __expf(dtv*A0), e1 = __expf(dtv*A1), e2 = __expf(dtv*A2), e3 = __expf(dtv*A3);
      h0 = e0*h0 + bs*Bv.x; h1 = e1*h1 + bs*Bv.y; h2 = e2*h2 + bs*Bv.z; h3 = e3*h3 + bs*Bv.w;
      p0 *= e0; p1 *= e1; p2 *= e2; p3 *= e3;
    }
    __syncthreads();
    cur ^= 1;
  }
  const int base = chunk * 2048 + t * 4;
  float4 P4 = {p0,p1,p2,p3}; *(float4*)&Pb[base] = P4;
  float4 H4 = {h0,h1,h2,h3}; *(float4*)&he[base] = H4;
}

// K5 (phase B): sequential carry over chunks, 8 blocks x 256 threads, 16-deep prefetch.
// NOTE: hi aliases Pb — no __restrict__ here so program-order load/store is kept.
__global__ __launch_bounds__(256) void k5_carry(
    const float* Pb, const float* he, float* hi)
{
  const int q = blockIdx.x * 256 + threadIdx.x;   // chain id, 0..2047
  float pr[PF], er[PF];
  #pragma unroll
  for (int j = 0; j < PF; j++) {
    pr[j] = Pb[j * 2048 + q];
    er[j] = he[j * 2048 + q];
  }
  float h = 0.f;
  for (int k = 0; k < NCH; k += PF) {
    #pragma unroll
    for (int j = 0; j < PF; j++) {
      int kk = k + j;
      if (kk < NCH) {
        hi[kk * 2048 + q] = h;
        h = fmaf(pr[j], h, er[j]);
        int kn = kk + PF;
        if (kn < NCH) {
          pr[j] = Pb[kn * 2048 + q];
          er[j] = he[kn * 2048 + q];
        }
      }
    }
  }
}

// K6 (phase C): replay scan with carries, fused ys*C + D-skip + z-gate -> y
__global__ __launch_bounds__(512) void k6_scanC(
    const float* __restrict__ dt, const float* __restrict__ xc,
    const float* __restrict__ Bm, const float* __restrict__ Cm,
    const float* __restrict__ zs, const float* __restrict__ Alog,
    const float* __restrict__ Dsk, const float* __restrict__ hi,
    float* __restrict__ y)
{
  __shared__ float sdt[2][2048];
  __shared__ float sxc[2][2048];
  __shared__ float szs[2][2048];
  __shared__ float sBC[2][512];
  const int t = threadIdx.x;
  const int chunk = blockIdx.x;
  const int n0 = chunk * LCH;
  const int srow = t >> 5, scol = (t & 31) * 4;
  const int c = t >> 2, sq = t & 3;
  float4 al = *(const float4*)&Alog[t * 4];
  const float A0 = -__expf(al.x), A1 = -__expf(al.y), A2 = -__expf(al.z), A3 = -__expf(al.w);
  float4 h4 = *(const float4*)&hi[chunk * 2048 + t * 4];
  float h0 = h4.x, h1 = h4.y, h2 = h4.z, h3 = h4.w;
  const float Dc = Dsk[c];

  auto stage = [&](int cb, int buf) {
    int n = n0 + cb * 16 + srow;
    float4 vd = {0,0,0,0}, vx = {0,0,0,0}, vz = {0,0,0,0};
    if (n < N_SEQ) {
      vd = *(const float4*)&dt[n * 128 + scol];
      vx = *(const float4*)&xc[n * 128 + scol];
      vz = *(const float4*)&zs[n * 128 + scol];
    }
    *(float4*)&sdt[buf][srow * 128 + scol] = vd;
    *(float4*)&sxc[buf][srow * 128 + scol] = vx;
    *(float4*)&szs[buf][srow * 128 + scol] = vz;
    if (t < 128) {
      int sel = t >> 6;           // 0: B, 1: C
      int u = t & 63;
      int br = u >> 2, bq = (u & 3) * 4;
      int nb = n0 + cb * 16 + br;
      float4 v = {0,0,0,0};
      if (nb < N_SEQ) v = sel ? *(const float4*)&Cm[nb * 16 + bq]
                              : *(const float4*)&Bm[nb * 16 + bq];
      *(float4*)&sBC[buf][sel * 256 + br * 16 + bq] = v;
    }
  };

  stage(0, 0);
  __syncthreads();
  int cur = 0;
  for (int cb = 0; cb < 4; cb++) {
    if (cb + 1 < 4) stage(cb + 1, cur ^ 1);
    #pragma unroll
    for (int rl = 0; rl < 16; rl++) {
      float dtv = sdt[cur][rl * 128 + c];
      float xv  = sxc[cur][rl * 128 + c];
      float zv  = szs[cur][rl * 128 + c];
      float4 Bv = *(const float4*)&sBC[cur][rl * 16 + sq * 4];
      float4 Cv = *(const float4*)&sBC[cur][256 + rl * 16 + sq * 4];
      float bs = dtv * xv;
      float e0 = __expf(dtv*A0), e1 = __expf(dtv*A1), e2 = __expf(dtv*A2), e3 = __expf(dtv*A3);
      h0 = e0*h0 + bs*Bv.x; h1 = e1*h1 + bs*Bv.y; h2 = e2*h2 + bs*Bv.z; h3 = e3*h3 + bs*Bv.w;
      float part = h0*Cv.x + h1*Cv.y + h2*Cv.z + h3*Cv.w;
      part += __shfl_xor(part, 1, 64);
      part += __shfl_xor(part, 2, 64);
      int n = n0 + cb * 16 + rl;
      if (sq == 0 && n < N_SEQ) y[n * 128 + c] = (part + Dc * xv) * zv;
    }
    __syncthreads();
    cur ^= 1;
  }
}

// K6b: feat = y @ out_proj_w.T + feature ; es[n]=exp(logit), per-block sums   [512 threads]
__global__ __launch_bounds__(512) void k6b_out_attn(
    const float* __restrict__ y, const float* __restrict__ ow,
    const float* __restrict__ featg, const float* __restrict__ aw1,
    const float* __restrict__ ab1, const float* __restrict__ aw2,
    const float* __restrict__ ab2, float* __restrict__ es,
    float* __restrict__ absb)
{
  __shared__ float sm[8448 + 8704 + 1088 + 512];
  float* yl  = sm;               // [64][132]
  float* wo  = sm + 8448;        // [128][68], wo[k*68+f] = ow[f*128+k]
  float* aw  = wo + 8704;        // [16][68]
  float* prt = aw + 1088;        // [8][64]
  const int tid = threadIdx.x;
  const int base = blockIdx.x * 64;
  for (int idx = tid; idx < 64 * 128; idx += 512) {
    int r = idx >> 7, k = idx & 127;
    int n = base + r;
    yl[r * 132 + k] = (n < N_SEQ) ? y[n * 128 + k] : 0.f;
  }
  for (int idx = tid; idx < 64 * 128; idx += 512) {
    int f = idx >> 7, k = idx & 127;
    wo[k * 68 + f] = ow[idx];
  }
  for (int idx = tid; idx < 16 * 64; idx += 512) {
    int j = idx >> 6, f = idx & 63;
    aw[j * 68 + f] = aw1[idx];
  }
  __syncthreads();
  const int fg = tid & 15;
  const int rb = tid >> 4;       // rows rb, rb+32
  float acc[2][4];
  #pragma unroll
  for (int i = 0; i < 2; i++) {
    int n = base + rb + 32 * i;
    if (n < N_SEQ) {
      float4 fv = *(const float4*)&featg[n * 64 + fg * 4];
      acc[i][0]=fv.x; acc[i][1]=fv.y; acc[i][2]=fv.z; acc[i][3]=fv.w;
    } else { acc[i][0]=0; acc[i][1]=0; acc[i][2]=0; acc[i][3]=0; }
  }
  #pragma unroll 4
  for (int k = 0; k < 128; k += 4) {
    float4 y0 = *(const float4*)&yl[(rb +  0) * 132 + k];
    float4 y1 = *(const float4*)&yl[(rb + 32) * 132 + k];
    float4 w0 = *(const float4*)&wo[(k + 0) * 68 + fg * 4];
    float4 w1 = *(const float4*)&wo[(k + 1) * 68 + fg * 4];
    float4 w2 = *(const float4*)&wo[(k + 2) * 68 + fg * 4];
    float4 w3 = *(const float4*)&wo[(k + 3) * 68 + fg * 4];
    acc[0][0] += y0.x*w0.x + y0.y*w1.x + y0.z*w2.x + y0.w*w3.x;
    acc[0][1] += y0.x*w0.y + y0.y*w1.y + y0.z*w2.y + y0.w*w3.y;
    acc[0][2] += y0.x*w0.z + y0.y*w1.z + y0.z*w2.z + y0.w*w3.z;
    acc[0][3] += y0.x*w0.w + y0.y*w1.w + y0.z*w2.w + y0.w*w3.w;
    acc[1][0] += y1.x*w0.x + y1.y*w1.x + y1.z*w2.x + y1.w*w3.x;
    acc[1][1] += y1.x*w0.y + y1.y*w1.y + y1.z*w2.y + y1.w*w3.y;
    acc[1][2] += y1.x*w0.z + y1.y*w1.z + y1.z*w2.z + y1.w*w3.z;
    acc[1][3] += y1.x*w0.w + y1.y*w1.w + y1.z*w2.w + y1.w*w3.w;
  }
  __syncthreads();  // all yl reads done before aliasing as feat storage
  float* flds = sm;  // [64][68]
  #pragma unroll
  for (int i = 0; i < 2; i++) {
    int r = rb + 32 * i;
    float4 o = {acc[i][0], acc[i][1], acc[i][2], acc[i][3]};
    *(float4*)&flds[r * 68 + fg * 4] = o;
  }
  __syncthreads();
  const int r = tid & 63, jg = tid >> 6;   // jg 0..7
  float psum = 0.f;
  #pragma unroll
  for (int jj = 0; jj < 2; jj++) {
    int j = jg * 2 + jj;
    float d = ab1[j];
    #pragma unroll
    for (int k = 0; k < 64; k += 4) {
      float4 fv = *(const float4*)&flds[r * 68 + k];
      float4 wv = *(const float4*)&aw[j * 68 + k];
      d += DOT4(fv, wv);
    }
    psum += tanhf(d) * aw2[j];
  }
  prt[jg * 64 + r] = psum;
  __syncthreads();
  if (tid < 64) {
    int n = base + tid;
    float s = ab2[0];
    #pragma unroll
    for (int g = 0; g < 8; g++) s += prt[g * 64 + tid];
    float e = 0.f;
    if (n < N_SEQ) { e = __expf(s); es[n] = e; }
    #pragma unroll
    for (int off = 32; off > 0; off >>= 1) e += __shfl_down(e, off, 64);
    if (tid == 0) absb[blockIdx.x] = e;
  }
}

// K7b: each block sums absb itself -> inv; writes A_soft and per-block partial M
__global__ __launch_bounds__(256) void k7b_weighted(
    const float* __restrict__ es, const float* __restrict__ featg,
    const float* __restrict__ absb, float* __restrict__ out, float* __restrict__ Mp)
{
  __shared__ float ssum[256];
  __shared__ float prt[4 * 64];
  const int tid = threadIdx.x;
  const int base = blockIdx.x * 256;
  float s = 0.f;
  for (int i = tid; i < NCH; i += 256) s += absb[i];
  ssum[tid] = s; __syncthreads();
  for (int st = 128; st > 0; st >>= 1) { if (tid < st) ssum[tid] += ssum[tid + st]; __syncthreads(); }
  const float inv = 1.f / ssum[0];
  const int f = tid & 63, g = tid >> 6;
  float acc = 0.f;
  for (int rr = g; rr < 256; rr += 4) {
    int n = base + rr;
    if (n < N_SEQ) acc += es[n] * inv * featg[n * 64 + f];
  }
  prt[g * 64 + f] = acc;
  int n = base + tid;
  if (n < N_SEQ) out[64 + n] = es[n] * inv;
  __syncthreads();
  if (tid < 64) Mp[blockIdx.x * 64 + tid] = prt[tid] + prt[64 + tid] + prt[128 + tid] + prt[192 + tid];
}

// K7c: M = sum of partials
__global__ __launch_bounds__(64) void k7c_reduceM(
    const float* __restrict__ Mp, float* __restrict__ out)
{
  const int f = threadIdx.x;
  float s = 0.f;
  for (int b = 0; b < NB7; b++) s += Mp[b * 64 + f];
  out[f] = s;
}

extern "C" void kernel_launch(void* const* d_in, const int* in_sizes, int n_in,
                              void* d_out, int out_size, void* d_ws, size_t ws_size,
                              hipStream_t stream)
{
  const float* xp   = (const float*)d_in[0];
  const float* W1   = (const float*)d_in[1];
  const float* b1   = (const float*)d_in[2];
  const float* ipw  = (const float*)d_in[3];
  const float* cw   = (const float*)d_in[4];
  const float* cb   = (const float*)d_in[5];
  const float* xpw  = (const float*)d_in[6];
  const float* dtw  = (const float*)d_in[7];
  const float* dtb  = (const float*)d_in[8];
  const float* Alog = (const float*)d_in[9];
  const float* Dsk  = (const float*)d_in[10];
  const float* ow   = (const float*)d_in[11];
  const float* aw1  = (const float*)d_in[12];
  const float* ab1  = (const float*)d_in[13];
  const float* aw2  = (const float*)d_in[14];
  const float* ab2  = (const float*)d_in[15];

  float* ws = (float*)d_ws;
  float* feature = ws;                       // 1,280,000
  float* xz_x = feature + 1280000;           // 2,560,000 (y alias after k3)
  float* zs   = xz_x + 2560000;              // 2,560,000
  float* xc   = zs + 2560000;                // 2,560,000
  float* dt   = xc + 2560000;                // 2,560,000
  float* Bm   = dt + 2560000;                // 320,000
  float* Cm   = Bm + 320000;                 // 320,000
  float* Pb   = Cm + 320000;                 // 641,024 (hi alias after k5)
  float* he   = Pb + 641024;                 // 641,024
  float* esb  = he + 641024;                 // 20,000 (exp of logits)
  float* absb = esb + 20000;                 // 320 (per-block exp sums)
  float* Mp   = absb + 320;                  // 5,056
  ushort* whi = (ushort*)(Mp + 5056);        // 65,536 ushorts
  ushort* wlo = whi + 65536;                 // 65,536 ushorts
  float* hi   = Pb;
  float* yv   = xz_x;
  float* out  = (float*)d_out;

  k0_convW<<<256, 256, 0, stream>>>(W1, whi, wlo);
  k1_fused<<<625, 512, 0, stream>>>(xp, whi, wlo, b1, feature);
  k2_inproj<<<313, 256, 0, stream>>>(feature, ipw, xz_x, zs);
  k3_conv_proj<<<417, 512, 0, stream>>>(xz_x, cw, cb, xpw, dtw, dtb, xc, dt, Bm, Cm);
  k4_scanA<<<NCH, 512, 0, stream>>>(dt, xc, Bm, Alog, Pb, he);
  k5_carry<<<8, 256, 0, stream>>>(Pb, he, hi);
  k6_scanC<<<NCH, 512, 0, stream>>>(dt, xc, Bm, Cm, zs, Alog, Dsk, hi, yv);
  k6b_out_attn<<<313, 512, 0, stream>>>(yv, ow, feature, aw1, ab1, aw2, ab2, esb, absb);
  k7b_weighted<<<NB7, 256, 0, stream>>>(esb, feature, absb, out, Mp);
  k7c_reduceM<<<1, 64, 0, stream>>>(Mp, out);
}

// Round 15
// 196.681 us; speedup vs baseline: 1.6953x; 1.6953x over previous
//
#include <hip/hip_runtime.h>
#include <math.h>

#define N_SEQ 20000
#define LCH 64
#define NCH 313   // ceil(20000/64)
#define NB7 79    // ceil(20000/256)
#define PF 16     // k5 prefetch depth

#define DOT4(a,b) ((a).x*(b).x + (a).y*(b).y + (a).z*(b).z + (a).w*(b).w)

typedef __attribute__((ext_vector_type(8))) short short8b;   // 8 bf16 (4 VGPR)
typedef __attribute__((ext_vector_type(4))) float f32x4;

__device__ __forceinline__ float siluf(float v) { return v / (1.f + __expf(-v)); }

__device__ __forceinline__ ushort bf16rne(float f) {
  uint u = __float_as_uint(f);
  return (ushort)((u + 0x7fffu + ((u >> 16) & 1u)) >> 16);
}
__device__ __forceinline__ float bf2f(ushort h) { return __uint_as_float(((uint)h) << 16); }

// K0: one-time W1 f32 -> bf16 hi/lo planes (64x1024)
__global__ __launch_bounds__(256) void k0_convW(
    const float* __restrict__ W1, ushort* __restrict__ whi, ushort* __restrict__ wlo)
{
  int i = blockIdx.x * 256 + threadIdx.x;   // 65536 elems
  float v = W1[i];
  ushort h = bf16rne(v);
  whi[i] = h;
  wlo[i] = bf16rne(v - bf2f(h));
}

// K1: feature = relu(x_path @ W1.T + b1), fused bf16-split MFMA.
// 32-row tiles (grid 625 exact), 512 threads = 8 waves.
// 4-deep STATIC prefetch ring (named slots, rule-#20 safe).
__global__ __launch_bounds__(512) void k1_fused(
    const float* __restrict__ xp, const ushort* __restrict__ whi,
    const ushort* __restrict__ wlo, const float* __restrict__ b1,
    float* __restrict__ feat)
{
  __shared__ ushort a_hi[2][32 * 40];
  __shared__ ushort a_lo[2][32 * 40];
  __shared__ ushort b_hi[2][64 * 40];
  __shared__ ushort b_lo[2][64 * 40];
  const int tid = threadIdx.x;
  const int rb = blockIdx.x * 32;
  const int wv = tid >> 6, lane = tid & 63;
  const int i16 = lane & 15, kb = lane >> 4;
  const int rt = (wv >> 2) * 16;
  const int ct = (wv & 3) * 16;
  const bool isA = tid < 256;          // waves 0-3 stage A, waves 4-7 stage B
  const int asrow = tid >> 3;          // 0..31
  const int askq = (tid & 7) * 4;      // k offset (f32 lanes)
  const int bsid = tid - 256;
  const int brow = bsid >> 2;          // 0..63
  const int bkq = (bsid & 3) * 8;      // k offset (ushort lanes)

  float4 ar0, ar1, ar2, ar3;
  uint4 bh0, bh1, bh2, bh3, bl0, bl1, bl2, bl3;

  auto issue = [&](int ks, float4& ar, uint4& bh, uint4& bl) {
    const int k0 = ks * 32;
    if (isA) {
      ar = *(const float4*)&xp[(size_t)(rb + asrow) * 1024 + k0 + askq];
    } else {
      size_t off = (size_t)brow * 1024 + k0 + bkq;
      bh = *(const uint4*)&whi[off];
      bl = *(const uint4*)&wlo[off];
    }
  };
  auto writeb = [&](const float4& ar, const uint4& bh, const uint4& bl, int buf) {
    if (isA) {
      ushort4 h, l;
      h.x = bf16rne(ar.x); l.x = bf16rne(ar.x - bf2f(h.x));
      h.y = bf16rne(ar.y); l.y = bf16rne(ar.y - bf2f(h.y));
      h.z = bf16rne(ar.z); l.z = bf16rne(ar.z - bf2f(h.z));
      h.w = bf16rne(ar.w); l.w = bf16rne(ar.w - bf2f(h.w));
      *(ushort4*)&a_hi[buf][asrow * 40 + askq] = h;
      *(ushort4*)&a_lo[buf][asrow * 40 + askq] = l;
    } else {
      *(uint4*)&b_hi[buf][brow * 40 + bkq] = bh;
      *(uint4*)&b_lo[buf][brow * 40 + bkq] = bl;
    }
  };
  const int koff = kb * 8;
  f32x4 acc = (f32x4){0.f, 0.f, 0.f, 0.f};

#define K1_MFMA(CBUF) { \
    short8b ahf = *(const short8b*)&a_hi[CBUF][(rt + i16) * 40 + koff]; \
    short8b alf = *(const short8b*)&a_lo[CBUF][(rt + i16) * 40 + koff]; \
    short8b bhf = *(const short8b*)&b_hi[CBUF][(ct + i16) * 40 + koff]; \
    short8b blf = *(const short8b*)&b_lo[CBUF][(ct + i16) * 40 + koff]; \
    acc = __builtin_amdgcn_mfma_f32_16x16x32_bf16(ahf, bhf, acc, 0, 0, 0); \
    acc = __builtin_amdgcn_mfma_f32_16x16x32_bf16(ahf, blf, acc, 0, 0, 0); \
    acc = __builtin_amdgcn_mfma_f32_16x16x32_bf16(alf, bhf, acc, 0, 0, 0); \
  }
#define K1_PHASE(P, AI, BHI, BLI, AW, BHW, BLW, CBUF, WBUF) \
  if ((P) + 4 < 32) issue((P) + 4, AI, BHI, BLI); \
  K1_MFMA(CBUF) \
  if ((P) + 1 < 32) writeb(AW, BHW, BLW, WBUF); \
  __syncthreads();

  issue(0, ar0, bh0, bl0);
  issue(1, ar1, bh1, bl1);
  issue(2, ar2, bh2, bl2);
  issue(3, ar3, bh3, bl3);
  writeb(ar0, bh0, bl0, 0);
  __syncthreads();
  for (int t = 0; t < 32; t += 4) {
    K1_PHASE(t + 0, ar0, bh0, bl0, ar1, bh1, bl1, 0, 1)
    K1_PHASE(t + 1, ar1, bh1, bl1, ar2, bh2, bl2, 1, 0)
    K1_PHASE(t + 2, ar2, bh2, bl2, ar3, bh3, bl3, 0, 1)
    K1_PHASE(t + 3, ar3, bh3, bl3, ar0, bh0, bl0, 1, 0)
  }
#undef K1_PHASE
#undef K1_MFMA
  // D: row = rt + kb*4 + r, col = ct + i16 ; 625*32 = 20000 exact, no bounds
  const int col = ct + i16;
  const float bb = b1[col];
  #pragma unroll
  for (int r = 0; r < 4; r++) {
    int n = rb + rt + kb * 4 + r;
    feat[n * 64 + col] = fmaxf(acc[r] + bb, 0.f);
  }
}

// K2: xz = feature @ in_proj_w.T ; split -> xz_x (raw), zs = silu(z)
// grid (313, 4): 64-row x 64-col tiles, K=64 staged in 32-chunks.
// PROVEN VGPR-64 form — do NOT restructure (rounds 2/8/14 all spilled to scratch).
__global__ __launch_bounds__(256) void k2_inproj(
    const float* __restrict__ featg, const float* __restrict__ ipw,
    float* __restrict__ xz_x, float* __restrict__ zs)
{
  __shared__ float fs[32][68];   // [k][row]
  __shared__ float wl[32][68];   // [k][col]
  const int tid = threadIdx.x;
  const int rb = blockIdx.x * 64;
  const int cb = blockIdx.y * 64;
  const int tr = tid >> 4, tc = tid & 15;
  float acc[4][4] = {};
  for (int k0 = 0; k0 < 64; k0 += 32) {
    #pragma unroll
    for (int i = 0; i < 8; i++) {
      int idx = tid + i * 256;
      int r = idx >> 5, k = idx & 31;
      int n = rb + r;
      fs[k][r] = (n < N_SEQ) ? featg[n * 64 + k0 + k] : 0.f;
      wl[k][r] = ipw[(cb + r) * 64 + k0 + k];
    }
    __syncthreads();
    #pragma unroll
    for (int k = 0; k < 32; k++) {
      float4 xv = *(const float4*)&fs[k][tr * 4];
      float4 wv = *(const float4*)&wl[k][tc * 4];
      acc[0][0] += xv.x*wv.x; acc[0][1] += xv.x*wv.y; acc[0][2] += xv.x*wv.z; acc[0][3] += xv.x*wv.w;
      acc[1][0] += xv.y*wv.x; acc[1][1] += xv.y*wv.y; acc[1][2] += xv.y*wv.z; acc[1][3] += xv.y*wv.w;
      acc[2][0] += xv.z*wv.x; acc[2][1] += xv.z*wv.y; acc[2][2] += xv.z*wv.z; acc[2][3] += xv.z*wv.w;
      acc[3][0] += xv.w*wv.x; acc[3][1] += xv.w*wv.y; acc[3][2] += xv.w*wv.z; acc[3][3] += xv.w*wv.w;
    }
    __syncthreads();
  }
  const int c0 = cb + tc * 4;
  #pragma unroll
  for (int i = 0; i < 4; i++) {
    int n = rb + tr * 4 + i;
    if (n < N_SEQ) {
      if (cb < 128) {
        float4 o = {acc[i][0], acc[i][1], acc[i][2], acc[i][3]};
        *(float4*)&xz_x[n * 128 + c0] = o;
      } else {
        float4 o = {siluf(acc[i][0]), siluf(acc[i][1]), siluf(acc[i][2]), siluf(acc[i][3])};
        *(float4*)&zs[n * 128 + c0 - 128] = o;
      }
    }
  }
}

// K3: causal depthwise conv + silu -> xc ; x_dbl = xc @ x_proj_w.T -> dt_raw,B,C ;
//     dt = softplus(dt_raw @ dt_proj_w.T + dt_proj_b)   [512 threads]
__global__ __launch_bounds__(512) void k3_conv_proj(
    const float* __restrict__ xz_x, const float* __restrict__ cw,
    const float* __restrict__ cb, const float* __restrict__ xpw,
    const float* __restrict__ dtw, const float* __restrict__ dtb,
    float* __restrict__ xc, float* __restrict__ dt,
    float* __restrict__ Bm, float* __restrict__ Cm)
{
  __shared__ float xzl[51 * 128];
  __shared__ float xcl[48 * 128];
  __shared__ float xwl[36 * 132];
  __shared__ float dtrl[48 * 4];
  const int tid = threadIdx.x;
  const int r0 = blockIdx.x * 48;
  for (int idx = tid; idx < 51 * 128; idx += 512) {
    int rg = r0 - 3 + (idx >> 7);
    int c = idx & 127;
    xzl[idx] = (rg >= 0 && rg < N_SEQ) ? xz_x[rg * 128 + c] : 0.f;
  }
  for (int idx = tid; idx < 36 * 128; idx += 512) {
    int j = idx >> 7, c = idx & 127;
    xwl[j * 132 + c] = xpw[idx];
  }
  __syncthreads();
  const int c = tid & 127;
  const int rbase = tid >> 7;  // 0..3
  const float4 cw4 = *(const float4*)&cw[c * 4];
  const float cbv = cb[c];
  #pragma unroll
  for (int i = 0; i < 12; i++) {
    int rl = rbase + 4 * i;
    float v = cw4.x * xzl[(rl+0)*128 + c] + cw4.y * xzl[(rl+1)*128 + c]
            + cw4.z * xzl[(rl+2)*128 + c] + cw4.w * xzl[(rl+3)*128 + c] + cbv;
    v = siluf(v);
    xcl[rl * 128 + c] = v;
    int n = r0 + rl;
    if (n < N_SEQ) xc[n * 128 + c] = v;
  }
  __syncthreads();
  for (int idx = tid; idx < 48 * 36; idx += 512) {
    int r = idx / 36, j = idx - r * 36;
    float s = 0.f;
    #pragma unroll
    for (int k = 0; k < 128; k += 4) {
      float4 a = *(const float4*)&xcl[r * 128 + k];
      float4 b = *(const float4*)&xwl[j * 132 + k];
      s += DOT4(a, b);
    }
    int n = r0 + r;
    if (j < 4) dtrl[r * 4 + j] = s;
    else if (n < N_SEQ) {
      if (j < 20) Bm[n * 16 + (j - 4)] = s;
      else        Cm[n * 16 + (j - 20)] = s;
    }
  }
  __syncthreads();
  const float4 dw4 = *(const float4*)&dtw[c * 4];
  const float dbv = dtb[c];
  #pragma unroll
  for (int i = 0; i < 12; i++) {
    int rl = rbase + 4 * i;
    int n = r0 + rl;
    if (n < N_SEQ) {
      float4 dr = *(const float4*)&dtrl[rl * 4];
      float v = DOT4(dr, dw4) + dbv;
      dt[n * 128 + c] = (v > 20.f) ? v : log1pf(__expf(v));
    }
  }
}

// K4 (phase A): per-chunk P and local scan end, LDS chunk-staged (16 rows/chunk, dbuf)
__global__ __launch_bounds__(512) void k4_scanA(
    const float* __restrict__ dt, const float* __restrict__ xc,
    const float* __restrict__ Bm, const float* __restrict__ Alog,
    float* __restrict__ Pb, float* __restrict__ he)
{
  __shared__ float sdt[2][2048];
  __shared__ float sxc[2][2048];
  __shared__ float sB[2][256];
  const int t = threadIdx.x;
  const int chunk = blockIdx.x;
  const int n0 = chunk * LCH;
  const int srow = t >> 5, scol = (t & 31) * 4;
  const int c = t >> 2, sq = t & 3;
  float4 al = *(const float4*)&Alog[t * 4];
  const float A0 = -__expf(al.x), A1 = -__expf(al.y), A2 = -__expf(al.z), A3 = -__expf(al.w);
  float h0=0,h1=0,h2=0,h3=0;
  float p0=1,p1=1,p2=1,p3=1;

  auto stage = [&](int cb, int buf) {
    int n = n0 + cb * 16 + srow;
    float4 vd = {0,0,0,0}, vx = {0,0,0,0};
    if (n < N_SEQ) {
      vd = *(const float4*)&dt[n * 128 + scol];
      vx = *(const float4*)&xc[n * 128 + scol];
    }
    *(float4*)&sdt[buf][srow * 128 + scol] = vd;
    *(float4*)&sxc[buf][srow * 128 + scol] = vx;
    if (t < 64) {
      int br = t >> 2, bq = (t & 3) * 4;
      int nb = n0 + cb * 16 + br;
      float4 vb = {0,0,0,0};
      if (nb < N_SEQ) vb = *(const float4*)&Bm[nb * 16 + bq];
      *(float4*)&sB[buf][br * 16 + bq] = vb;
    }
  };

  stage(0, 0);
  __syncthreads();
  int cur = 0;
  for (int cb = 0; cb < 4; cb++) {
    if (cb + 1 < 4) stage(cb + 1, cur ^ 1);
    #pragma unroll
    for (int rl = 0; rl < 16; rl++) {
      float dtv = sdt[cur][rl * 128 + c];
      float xv  = sxc[cur][rl * 128 + c];
      float4 Bv = *(const float4*)&sB[cur][rl * 16 + sq * 4];
      float bs = dtv * xv;
      float e0 = __expf(dtv*A0), e1 = __expf(dtv*A1), e2 = __expf(dtv*A2), e3 = __expf(dtv*A3);
      h0 = e0*h0 + bs*Bv.x; h1 = e1*h1 + bs*Bv.y; h2 = e2*h2 + bs*Bv.z; h3 = e3*h3 + bs*Bv.w;
      p0 *= e0; p1 *= e1; p2 *= e2; p3 *= e3;
    }
    __syncthreads();
    cur ^= 1;
  }
  const int base = chunk * 2048 + t * 4;
  float4 P4 = {p0,p1,p2,p3}; *(float4*)&Pb[base] = P4;
  float4 H4 = {h0,h1,h2,h3}; *(float4*)&he[base] = H4;
}

// K5 (phase B): sequential carry over chunks, 8 blocks x 256 threads, 16-deep prefetch.
// NOTE: hi aliases Pb — no __restrict__ here so program-order load/store is kept.
__global__ __launch_bounds__(256) void k5_carry(
    const float* Pb, const float* he, float* hi)
{
  const int q = blockIdx.x * 256 + threadIdx.x;   // chain id, 0..2047
  float pr[PF], er[PF];
  #pragma unroll
  for (int j = 0; j < PF; j++) {
    pr[j] = Pb[j * 2048 + q];
    er[j] = he[j * 2048 + q];
  }
  float h = 0.f;
  for (int k = 0; k < NCH; k += PF) {
    #pragma unroll
    for (int j = 0; j < PF; j++) {
      int kk = k + j;
      if (kk < NCH) {
        hi[kk * 2048 + q] = h;
        h = fmaf(pr[j], h, er[j]);
        int kn = kk + PF;
        if (kn < NCH) {
          pr[j] = Pb[kn * 2048 + q];
          er[j] = he[kn * 2048 + q];
        }
      }
    }
  }
}

// K6 (phase C): replay scan with carries, fused ys*C + D-skip + z-gate -> y
__global__ __launch_bounds__(512) void k6_scanC(
    const float* __restrict__ dt, const float* __restrict__ xc,
    const float* __restrict__ Bm, const float* __restrict__ Cm,
    const float* __restrict__ zs, const float* __restrict__ Alog,
    const float* __restrict__ Dsk, const float* __restrict__ hi,
    float* __restrict__ y)
{
  __shared__ float sdt[2][2048];
  __shared__ float sxc[2][2048];
  __shared__ float szs[2][2048];
  __shared__ float sBC[2][512];
  const int t = threadIdx.x;
  const int chunk = blockIdx.x;
  const int n0 = chunk * LCH;
  const int srow = t >> 5, scol = (t & 31) * 4;
  const int c = t >> 2, sq = t & 3;
  float4 al = *(const float4*)&Alog[t * 4];
  const float A0 = -__expf(al.x), A1 = -__expf(al.y), A2 = -__expf(al.z), A3 = -__expf(al.w);
  float4 h4 = *(const float4*)&hi[chunk * 2048 + t * 4];
  float h0 = h4.x, h1 = h4.y, h2 = h4.z, h3 = h4.w;
  const float Dc = Dsk[c];

  auto stage = [&](int cb, int buf) {
    int n = n0 + cb * 16 + srow;
    float4 vd = {0,0,0,0}, vx = {0,0,0,0}, vz = {0,0,0,0};
    if (n < N_SEQ) {
      vd = *(const float4*)&dt[n * 128 + scol];
      vx = *(const float4*)&xc[n * 128 + scol];
      vz = *(const float4*)&zs[n * 128 + scol];
    }
    *(float4*)&sdt[buf][srow * 128 + scol] = vd;
    *(float4*)&sxc[buf][srow * 128 + scol] = vx;
    *(float4*)&szs[buf][srow * 128 + scol] = vz;
    if (t < 128) {
      int sel = t >> 6;           // 0: B, 1: C
      int u = t & 63;
      int br = u >> 2, bq = (u & 3) * 4;
      int nb = n0 + cb * 16 + br;
      float4 v = {0,0,0,0};
      if (nb < N_SEQ) v = sel ? *(const float4*)&Cm[nb * 16 + bq]
                              : *(const float4*)&Bm[nb * 16 + bq];
      *(float4*)&sBC[buf][sel * 256 + br * 16 + bq] = v;
    }
  };

  stage(0, 0);
  __syncthreads();
  int cur = 0;
  for (int cb = 0; cb < 4; cb++) {
    if (cb + 1 < 4) stage(cb + 1, cur ^ 1);
    #pragma unroll
    for (int rl = 0; rl < 16; rl++) {
      float dtv = sdt[cur][rl * 128 + c];
      float xv  = sxc[cur][rl * 128 + c];
      float zv  = szs[cur][rl * 128 + c];
      float4 Bv = *(const float4*)&sBC[cur][rl * 16 + sq * 4];
      float4 Cv = *(const float4*)&sBC[cur][256 + rl * 16 + sq * 4];
      float bs = dtv * xv;
      float e0 = __expf(dtv*A0), e1 = __expf(dtv*A1), e2 = __expf(dtv*A2), e3 = __expf(dtv*A3);
      h0 = e0*h0 + bs*Bv.x; h1 = e1*h1 + bs*Bv.y; h2 = e2*h2 + bs*Bv.z; h3 = e3*h3 + bs*Bv.w;
      float part = h0*Cv.x + h1*Cv.y + h2*Cv.z + h3*Cv.w;
      part += __shfl_xor(part, 1, 64);
      part += __shfl_xor(part, 2, 64);
      int n = n0 + cb * 16 + rl;
      if (sq == 0 && n < N_SEQ) y[n * 128 + c] = (part + Dc * xv) * zv;
    }
    __syncthreads();
    cur ^= 1;
  }
}

// K6b: feat = y @ out_proj_w.T + feature ; es[n]=exp(logit), per-block sums   [512 threads]
__global__ __launch_bounds__(512) void k6b_out_attn(
    const float* __restrict__ y, const float* __restrict__ ow,
    const float* __restrict__ featg, const float* __restrict__ aw1,
    const float* __restrict__ ab1, const float* __restrict__ aw2,
    const float* __restrict__ ab2, float* __restrict__ es,
    float* __restrict__ absb)
{
  __shared__ float sm[8448 + 8704 + 1088 + 512];
  float* yl  = sm;               // [64][132]
  float* wo  = sm + 8448;        // [128][68], wo[k*68+f] = ow[f*128+k]
  float* aw  = wo + 8704;        // [16][68]
  float* prt = aw + 1088;        // [8][64]
  const int tid = threadIdx.x;
  const int base = blockIdx.x * 64;
  for (int idx = tid; idx < 64 * 128; idx += 512) {
    int r = idx >> 7, k = idx & 127;
    int n = base + r;
    yl[r * 132 + k] = (n < N_SEQ) ? y[n * 128 + k] : 0.f;
  }
  for (int idx = tid; idx < 64 * 128; idx += 512) {
    int f = idx >> 7, k = idx & 127;
    wo[k * 68 + f] = ow[idx];
  }
  for (int idx = tid; idx < 16 * 64; idx += 512) {
    int j = idx >> 6, f = idx & 63;
    aw[j * 68 + f] = aw1[idx];
  }
  __syncthreads();
  const int fg = tid & 15;
  const int rb = tid >> 4;       // rows rb, rb+32
  float acc[2][4];
  #pragma unroll
  for (int i = 0; i < 2; i++) {
    int n = base + rb + 32 * i;
    if (n < N_SEQ) {
      float4 fv = *(const float4*)&featg[n * 64 + fg * 4];
      acc[i][0]=fv.x; acc[i][1]=fv.y; acc[i][2]=fv.z; acc[i][3]=fv.w;
    } else { acc[i][0]=0; acc[i][1]=0; acc[i][2]=0; acc[i][3]=0; }
  }
  #pragma unroll 4
  for (int k = 0; k < 128; k += 4) {
    float4 y0 = *(const float4*)&yl[(rb +  0) * 132 + k];
    float4 y1 = *(const float4*)&yl[(rb + 32) * 132 + k];
    float4 w0 = *(const float4*)&wo[(k + 0) * 68 + fg * 4];
    float4 w1 = *(const float4*)&wo[(k + 1) * 68 + fg * 4];
    float4 w2 = *(const float4*)&wo[(k + 2) * 68 + fg * 4];
    float4 w3 = *(const float4*)&wo[(k + 3) * 68 + fg * 4];
    acc[0][0] += y0.x*w0.x + y0.y*w1.x + y0.z*w2.x + y0.w*w3.x;
    acc[0][1] += y0.x*w0.y + y0.y*w1.y + y0.z*w2.y + y0.w*w3.y;
    acc[0][2] += y0.x*w0.z + y0.y*w1.z + y0.z*w2.z + y0.w*w3.z;
    acc[0][3] += y0.x*w0.w + y0.y*w1.w + y0.z*w2.w + y0.w*w3.w;
    acc[1][0] += y1.x*w0.x + y1.y*w1.x + y1.z*w2.x + y1.w*w3.x;
    acc[1][1] += y1.x*w0.y + y1.y*w1.y + y1.z*w2.y + y1.w*w3.y;
    acc[1][2] += y1.x*w0.z + y1.y*w1.z + y1.z*w2.z + y1.w*w3.z;
    acc[1][3] += y1.x*w0.w + y1.y*w1.w + y1.z*w2.w + y1.w*w3.w;
  }
  __syncthreads();  // all yl reads done before aliasing as feat storage
  float* flds = sm;  // [64][68]
  #pragma unroll
  for (int i = 0; i < 2; i++) {
    int r = rb + 32 * i;
    float4 o = {acc[i][0], acc[i][1], acc[i][2], acc[i][3]};
    *(float4*)&flds[r * 68 + fg * 4] = o;
  }
  __syncthreads();
  const int r = tid & 63, jg = tid >> 6;   // jg 0..7
  float psum = 0.f;
  #pragma unroll
  for (int jj = 0; jj < 2; jj++) {
    int j = jg * 2 + jj;
    float d = ab1[j];
    #pragma unroll
    for (int k = 0; k < 64; k += 4) {
      float4 fv = *(const float4*)&flds[r * 68 + k];
      float4 wv = *(const float4*)&aw[j * 68 + k];
      d += DOT4(fv, wv);
    }
    psum += tanhf(d) * aw2[j];
  }
  prt[jg * 64 + r] = psum;
  __syncthreads();
  if (tid < 64) {
    int n = base + tid;
    float s = ab2[0];
    #pragma unroll
    for (int g = 0; g < 8; g++) s += prt[g * 64 + tid];
    float e = 0.f;
    if (n < N_SEQ) { e = __expf(s); es[n] = e; }
    #pragma unroll
    for (int off = 32; off > 0; off >>= 1) e += __shfl_down(e, off, 64);
    if (tid == 0) absb[blockIdx.x] = e;
  }
}

// K7b: each block sums absb itself -> inv; writes A_soft and per-block partial M
__global__ __launch_bounds__(256) void k7b_weighted(
    const float* __restrict__ es, const float* __restrict__ featg,
    const float* __restrict__ absb, float* __restrict__ out, float* __restrict__ Mp)
{
  __shared__ float ssum[256];
  __shared__ float prt[4 * 64];
  const int tid = threadIdx.x;
  const int base = blockIdx.x * 256;
  float s = 0.f;
  for (int i = tid; i < NCH; i += 256) s += absb[i];
  ssum[tid] = s; __syncthreads();
  for (int st = 128; st > 0; st >>= 1) { if (tid < st) ssum[tid] += ssum[tid + st]; __syncthreads(); }
  const float inv = 1.f / ssum[0];
  const int f = tid & 63, g = tid >> 6;
  float acc = 0.f;
  for (int rr = g; rr < 256; rr += 4) {
    int n = base + rr;
    if (n < N_SEQ) acc += es[n] * inv * featg[n * 64 + f];
  }
  prt[g * 64 + f] = acc;
  int n = base + tid;
  if (n < N_SEQ) out[64 + n] = es[n] * inv;
  __syncthreads();
  if (tid < 64) Mp[blockIdx.x * 64 + tid] = prt[tid] + prt[64 + tid] + prt[128 + tid] + prt[192 + tid];
}

// K7c: M = sum of partials
__global__ __launch_bounds__(64) void k7c_reduceM(
    const float* __restrict__ Mp, float* __restrict__ out)
{
  const int f = threadIdx.x;
  float s = 0.f;
  for (int b = 0; b < NB7; b++) s += Mp[b * 64 + f];
  out[f] = s;
}

extern "C" void kernel_launch(void* const* d_in, const int* in_sizes, int n_in,
                              void* d_out, int out_size, void* d_ws, size_t ws_size,
                              hipStream_t stream)
{
  const float* xp   = (const float*)d_in[0];
  const float* W1   = (const float*)d_in[1];
  const float* b1   = (const float*)d_in[2];
  const float* ipw  = (const float*)d_in[3];
  const float* cw   = (const float*)d_in[4];
  const float* cb   = (const float*)d_in[5];
  const float* xpw  = (const float*)d_in[6];
  const float* dtw  = (const float*)d_in[7];
  const float* dtb  = (const float*)d_in[8];
  const float* Alog = (const float*)d_in[9];
  const float* Dsk  = (const float*)d_in[10];
  const float* ow   = (const float*)d_in[11];
  const float* aw1  = (const float*)d_in[12];
  const float* ab1  = (const float*)d_in[13];
  const float* aw2  = (const float*)d_in[14];
  const float* ab2  = (const float*)d_in[15];

  float* ws = (float*)d_ws;
  float* feature = ws;                       // 1,280,000
  float* xz_x = feature + 1280000;           // 2,560,000 (y alias after k3)
  float* zs   = xz_x + 2560000;              // 2,560,000
  float* xc   = zs + 2560000;                // 2,560,000
  float* dt   = xc + 2560000;                // 2,560,000
  float* Bm   = dt + 2560000;                // 320,000
  float* Cm   = Bm + 320000;                 // 320,000
  float* Pb   = Cm + 320000;                 // 641,024 (hi alias after k5)
  float* he   = Pb + 641024;                 // 641,024
  float* esb  = he + 641024;                 // 20,000 (exp of logits)
  float* absb = esb + 20000;                 // 320 (per-block exp sums)
  float* Mp   = absb + 320;                  // 5,056
  ushort* whi = (ushort*)(Mp + 5056);        // 65,536 ushorts
  ushort* wlo = whi + 65536;                 // 65,536 ushorts
  float* hi   = Pb;
  float* yv   = xz_x;
  float* out  = (float*)d_out;

  k0_convW<<<256, 256, 0, stream>>>(W1, whi, wlo);
  k1_fused<<<625, 512, 0, stream>>>(xp, whi, wlo, b1, feature);
  k2_inproj<<<dim3(313, 4), 256, 0, stream>>>(feature, ipw, xz_x, zs);
  k3_conv_proj<<<417, 512, 0, stream>>>(xz_x, cw, cb, xpw, dtw, dtb, xc, dt, Bm, Cm);
  k4_scanA<<<NCH, 512, 0, stream>>>(dt, xc, Bm, Alog, Pb, he);
  k5_carry<<<8, 256, 0, stream>>>(Pb, he, hi);
  k6_scanC<<<NCH, 512, 0, stream>>>(dt, xc, Bm, Cm, zs, Alog, Dsk, hi, yv);
  k6b_out_attn<<<313, 512, 0, stream>>>(yv, ow, feature, aw1, ab1, aw2, ab2, esb, absb);
  k7b_weighted<<<NB7, 256, 0, stream>>>(esb, feature, absb, out, Mp);
  k7c_reduceM<<<1, 64, 0, stream>>>(Mp, out);
}

// Round 16
// 187.782 us; speedup vs baseline: 1.7756x; 1.0474x over previous
//
#include <hip/hip_runtime.h>
#include <math.h>

#define N_SEQ 20000
#define LCH 64
#define NCH 313   // ceil(20000/64)
#define NB7 79    // ceil(20000/256)
#define PF 16     // k5 prefetch depth

#define DOT4(a,b) ((a).x*(b).x + (a).y*(b).y + (a).z*(b).z + (a).w*(b).w)

typedef __attribute__((ext_vector_type(8))) short short8b;   // 8 bf16 (4 VGPR)
typedef __attribute__((ext_vector_type(4))) float f32x4;

__device__ __forceinline__ float siluf(float v) { return v / (1.f + __expf(-v)); }

__device__ __forceinline__ ushort bf16rne(float f) {
  uint u = __float_as_uint(f);
  return (ushort)((u + 0x7fffu + ((u >> 16) & 1u)) >> 16);
}
__device__ __forceinline__ float bf2f(ushort h) { return __uint_as_float(((uint)h) << 16); }

// K0: one-time W1 f32 -> bf16 hi/lo planes (64x1024)
__global__ __launch_bounds__(256) void k0_convW(
    const float* __restrict__ W1, ushort* __restrict__ whi, ushort* __restrict__ wlo)
{
  int i = blockIdx.x * 256 + threadIdx.x;   // 65536 elems
  float v = W1[i];
  ushort h = bf16rne(v);
  whi[i] = h;
  wlo[i] = bf16rne(v - bf2f(h));
}

// K1: feature = relu(x_path @ W1.T + b1), fused bf16-split MFMA.
// 32-row tiles (grid 625 exact), 512 threads = 8 waves, wave w owns
// rows (w>>2)*16, cols (w&3)*16. 2-deep async-stage split with STATIC slot
// regs (R13 schedule — best measured; 4-deep ring regressed via occupancy).
__global__ __launch_bounds__(512) void k1_fused(
    const float* __restrict__ xp, const ushort* __restrict__ whi,
    const ushort* __restrict__ wlo, const float* __restrict__ b1,
    float* __restrict__ feat)
{
  __shared__ ushort a_hi[2][32 * 40];
  __shared__ ushort a_lo[2][32 * 40];
  __shared__ ushort b_hi[2][64 * 40];
  __shared__ ushort b_lo[2][64 * 40];
  const int tid = threadIdx.x;
  const int rb = blockIdx.x * 32;
  const int wv = tid >> 6, lane = tid & 63;
  const int i16 = lane & 15, kb = lane >> 4;
  const int rt = (wv >> 2) * 16;
  const int ct = (wv & 3) * 16;
  const bool isA = tid < 256;          // waves 0-3 stage A, waves 4-7 stage B
  const int asrow = tid >> 3;          // 0..31
  const int askq = (tid & 7) * 4;      // k offset (f32 lanes)
  const int bsid = tid - 256;
  const int brow = bsid >> 2;          // 0..63
  const int bkq = (bsid & 3) * 8;      // k offset (ushort lanes)

  float4 ar0, ar1;
  uint4 bh0, bh1, bl0, bl1;

  auto issue = [&](int ks, float4& ar, uint4& bh, uint4& bl) {
    const int k0 = ks * 32;
    if (isA) {
      ar = *(const float4*)&xp[(size_t)(rb + asrow) * 1024 + k0 + askq];
    } else {
      size_t off = (size_t)brow * 1024 + k0 + bkq;
      bh = *(const uint4*)&whi[off];
      bl = *(const uint4*)&wlo[off];
    }
  };
  auto writeb = [&](const float4& ar, const uint4& bh, const uint4& bl, int buf) {
    if (isA) {
      ushort4 h, l;
      h.x = bf16rne(ar.x); l.x = bf16rne(ar.x - bf2f(h.x));
      h.y = bf16rne(ar.y); l.y = bf16rne(ar.y - bf2f(h.y));
      h.z = bf16rne(ar.z); l.z = bf16rne(ar.z - bf2f(h.z));
      h.w = bf16rne(ar.w); l.w = bf16rne(ar.w - bf2f(h.w));
      *(ushort4*)&a_hi[buf][asrow * 40 + askq] = h;
      *(ushort4*)&a_lo[buf][asrow * 40 + askq] = l;
    } else {
      *(uint4*)&b_hi[buf][brow * 40 + bkq] = bh;
      *(uint4*)&b_lo[buf][brow * 40 + bkq] = bl;
    }
  };
  const int koff = kb * 8;
  f32x4 acc = (f32x4){0.f, 0.f, 0.f, 0.f};

  issue(0, ar0, bh0, bl0);
  issue(1, ar1, bh1, bl1);
  writeb(ar0, bh0, bl0, 0);
  __syncthreads();
  for (int t = 0; t < 32; t += 2) {
    // even: compute buf0 (chunk t), prefetch chunk t+2 -> slot0, write chunk t+1 -> buf1
    if (t + 2 < 32) issue(t + 2, ar0, bh0, bl0);
    {
      short8b ahf = *(const short8b*)&a_hi[0][(rt + i16) * 40 + koff];
      short8b alf = *(const short8b*)&a_lo[0][(rt + i16) * 40 + koff];
      short8b bhf = *(const short8b*)&b_hi[0][(ct + i16) * 40 + koff];
      short8b blf = *(const short8b*)&b_lo[0][(ct + i16) * 40 + koff];
      acc = __builtin_amdgcn_mfma_f32_16x16x32_bf16(ahf, bhf, acc, 0, 0, 0);
      acc = __builtin_amdgcn_mfma_f32_16x16x32_bf16(ahf, blf, acc, 0, 0, 0);
      acc = __builtin_amdgcn_mfma_f32_16x16x32_bf16(alf, bhf, acc, 0, 0, 0);
    }
    writeb(ar1, bh1, bl1, 1);
    __syncthreads();
    // odd: compute buf1 (chunk t+1), prefetch chunk t+3 -> slot1, write chunk t+2 -> buf0
    if (t + 3 < 32) issue(t + 3, ar1, bh1, bl1);
    {
      short8b ahf = *(const short8b*)&a_hi[1][(rt + i16) * 40 + koff];
      short8b alf = *(const short8b*)&a_lo[1][(rt + i16) * 40 + koff];
      short8b bhf = *(const short8b*)&b_hi[1][(ct + i16) * 40 + koff];
      short8b blf = *(const short8b*)&b_lo[1][(ct + i16) * 40 + koff];
      acc = __builtin_amdgcn_mfma_f32_16x16x32_bf16(ahf, bhf, acc, 0, 0, 0);
      acc = __builtin_amdgcn_mfma_f32_16x16x32_bf16(ahf, blf, acc, 0, 0, 0);
      acc = __builtin_amdgcn_mfma_f32_16x16x32_bf16(alf, bhf, acc, 0, 0, 0);
    }
    if (t + 2 < 32) writeb(ar0, bh0, bl0, 0);
    __syncthreads();
  }
  // D: row = rt + kb*4 + r, col = ct + i16 ; 625*32 = 20000 exact, no bounds
  const int col = ct + i16;
  const float bb = b1[col];
  #pragma unroll
  for (int r = 0; r < 4; r++) {
    int n = rb + rt + kb * 4 + r;
    feat[n * 64 + col] = fmaxf(acc[r] + bb, 0.f);
  }
}

// K2: xz = feature @ in_proj_w.T ; split -> xz_x (raw), zs = silu(z)
// grid (313, 4): 64-row x 64-col tiles, K=64 staged in 32-chunks.
// PROVEN VGPR-64 form — do NOT restructure (rounds 2/8/14 all spilled to scratch).
__global__ __launch_bounds__(256) void k2_inproj(
    const float* __restrict__ featg, const float* __restrict__ ipw,
    float* __restrict__ xz_x, float* __restrict__ zs)
{
  __shared__ float fs[32][68];   // [k][row]
  __shared__ float wl[32][68];   // [k][col]
  const int tid = threadIdx.x;
  const int rb = blockIdx.x * 64;
  const int cb = blockIdx.y * 64;
  const int tr = tid >> 4, tc = tid & 15;
  float acc[4][4] = {};
  for (int k0 = 0; k0 < 64; k0 += 32) {
    #pragma unroll
    for (int i = 0; i < 8; i++) {
      int idx = tid + i * 256;
      int r = idx >> 5, k = idx & 31;
      int n = rb + r;
      fs[k][r] = (n < N_SEQ) ? featg[n * 64 + k0 + k] : 0.f;
      wl[k][r] = ipw[(cb + r) * 64 + k0 + k];
    }
    __syncthreads();
    #pragma unroll
    for (int k = 0; k < 32; k++) {
      float4 xv = *(const float4*)&fs[k][tr * 4];
      float4 wv = *(const float4*)&wl[k][tc * 4];
      acc[0][0] += xv.x*wv.x; acc[0][1] += xv.x*wv.y; acc[0][2] += xv.x*wv.z; acc[0][3] += xv.x*wv.w;
      acc[1][0] += xv.y*wv.x; acc[1][1] += xv.y*wv.y; acc[1][2] += xv.y*wv.z; acc[1][3] += xv.y*wv.w;
      acc[2][0] += xv.z*wv.x; acc[2][1] += xv.z*wv.y; acc[2][2] += xv.z*wv.z; acc[2][3] += xv.z*wv.w;
      acc[3][0] += xv.w*wv.x; acc[3][1] += xv.w*wv.y; acc[3][2] += xv.w*wv.z; acc[3][3] += xv.w*wv.w;
    }
    __syncthreads();
  }
  const int c0 = cb + tc * 4;
  #pragma unroll
  for (int i = 0; i < 4; i++) {
    int n = rb + tr * 4 + i;
    if (n < N_SEQ) {
      if (cb < 128) {
        float4 o = {acc[i][0], acc[i][1], acc[i][2], acc[i][3]};
        *(float4*)&xz_x[n * 128 + c0] = o;
      } else {
        float4 o = {siluf(acc[i][0]), siluf(acc[i][1]), siluf(acc[i][2]), siluf(acc[i][3])};
        *(float4*)&zs[n * 128 + c0 - 128] = o;
      }
    }
  }
}

// K3: causal depthwise conv + silu -> xc ; x_dbl = xc @ x_proj_w.T -> dt_raw,B,C ;
//     dt = softplus(dt_raw @ dt_proj_w.T + dt_proj_b)   [512 threads]
__global__ __launch_bounds__(512) void k3_conv_proj(
    const float* __restrict__ xz_x, const float* __restrict__ cw,
    const float* __restrict__ cb, const float* __restrict__ xpw,
    const float* __restrict__ dtw, const float* __restrict__ dtb,
    float* __restrict__ xc, float* __restrict__ dt,
    float* __restrict__ Bm, float* __restrict__ Cm)
{
  __shared__ float xzl[51 * 128];
  __shared__ float xcl[48 * 128];
  __shared__ float xwl[36 * 132];
  __shared__ float dtrl[48 * 4];
  const int tid = threadIdx.x;
  const int r0 = blockIdx.x * 48;
  for (int idx = tid; idx < 51 * 128; idx += 512) {
    int rg = r0 - 3 + (idx >> 7);
    int c = idx & 127;
    xzl[idx] = (rg >= 0 && rg < N_SEQ) ? xz_x[rg * 128 + c] : 0.f;
  }
  for (int idx = tid; idx < 36 * 128; idx += 512) {
    int j = idx >> 7, c = idx & 127;
    xwl[j * 132 + c] = xpw[idx];
  }
  __syncthreads();
  const int c = tid & 127;
  const int rbase = tid >> 7;  // 0..3
  const float4 cw4 = *(const float4*)&cw[c * 4];
  const float cbv = cb[c];
  #pragma unroll
  for (int i = 0; i < 12; i++) {
    int rl = rbase + 4 * i;
    float v = cw4.x * xzl[(rl+0)*128 + c] + cw4.y * xzl[(rl+1)*128 + c]
            + cw4.z * xzl[(rl+2)*128 + c] + cw4.w * xzl[(rl+3)*128 + c] + cbv;
    v = siluf(v);
    xcl[rl * 128 + c] = v;
    int n = r0 + rl;
    if (n < N_SEQ) xc[n * 128 + c] = v;
  }
  __syncthreads();
  for (int idx = tid; idx < 48 * 36; idx += 512) {
    int r = idx / 36, j = idx - r * 36;
    float s = 0.f;
    #pragma unroll
    for (int k = 0; k < 128; k += 4) {
      float4 a = *(const float4*)&xcl[r * 128 + k];
      float4 b = *(const float4*)&xwl[j * 132 + k];
      s += DOT4(a, b);
    }
    int n = r0 + r;
    if (j < 4) dtrl[r * 4 + j] = s;
    else if (n < N_SEQ) {
      if (j < 20) Bm[n * 16 + (j - 4)] = s;
      else        Cm[n * 16 + (j - 20)] = s;
    }
  }
  __syncthreads();
  const float4 dw4 = *(const float4*)&dtw[c * 4];
  const float dbv = dtb[c];
  #pragma unroll
  for (int i = 0; i < 12; i++) {
    int rl = rbase + 4 * i;
    int n = r0 + rl;
    if (n < N_SEQ) {
      float4 dr = *(const float4*)&dtrl[rl * 4];
      float v = DOT4(dr, dw4) + dbv;
      dt[n * 128 + c] = (v > 20.f) ? v : log1pf(__expf(v));
    }
  }
}

// K4 (phase A): per-chunk P and local scan end, LDS chunk-staged (16 rows/chunk, dbuf)
__global__ __launch_bounds__(512) void k4_scanA(
    const float* __restrict__ dt, const float* __restrict__ xc,
    const float* __restrict__ Bm, const float* __restrict__ Alog,
    float* __restrict__ Pb, float* __restrict__ he)
{
  __shared__ float sdt[2][2048];
  __shared__ float sxc[2][2048];
  __shared__ float sB[2][256];
  const int t = threadIdx.x;
  const int chunk = blockIdx.x;
  const int n0 = chunk * LCH;
  const int srow = t >> 5, scol = (t & 31) * 4;
  const int c = t >> 2, sq = t & 3;
  float4 al = *(const float4*)&Alog[t * 4];
  const float A0 = -__expf(al.x), A1 = -__expf(al.y), A2 = -__expf(al.z), A3 = -__expf(al.w);
  float h0=0,h1=0,h2=0,h3=0;
  float p0=1,p1=1,p2=1,p3=1;

  auto stage = [&](int cb, int buf) {
    int n = n0 + cb * 16 + srow;
    float4 vd = {0,0,0,0}, vx = {0,0,0,0};
    if (n < N_SEQ) {
      vd = *(const float4*)&dt[n * 128 + scol];
      vx = *(const float4*)&xc[n * 128 + scol];
    }
    *(float4*)&sdt[buf][srow * 128 + scol] = vd;
    *(float4*)&sxc[buf][srow * 128 + scol] = vx;
    if (t < 64) {
      int br = t >> 2, bq = (t & 3) * 4;
      int nb = n0 + cb * 16 + br;
      float4 vb = {0,0,0,0};
      if (nb < N_SEQ) vb = *(const float4*)&Bm[nb * 16 + bq];
      *(float4*)&sB[buf][br * 16 + bq] = vb;
    }
  };

  stage(0, 0);
  __syncthreads();
  int cur = 0;
  for (int cb = 0; cb < 4; cb++) {
    if (cb + 1 < 4) stage(cb + 1, cur ^ 1);
    #pragma unroll
    for (int rl = 0; rl < 16; rl++) {
      float dtv = sdt[cur][rl * 128 + c];
      float xv  = sxc[cur][rl * 128 + c];
      float4 Bv = *(const float4*)&sB[cur][rl * 16 + sq * 4];
      float bs = dtv * xv;
      float e0 = __expf(dtv*A0), e1 = __expf(dtv*A1), e2 = __expf(dtv*A2), e3 = __expf(dtv*A3);
      h0 = e0*h0 + bs*Bv.x; h1 = e1*h1 + bs*Bv.y; h2 = e2*h2 + bs*Bv.z; h3 = e3*h3 + bs*Bv.w;
      p0 *= e0; p1 *= e1; p2 *= e2; p3 *= e3;
    }
    __syncthreads();
    cur ^= 1;
  }
  const int base = chunk * 2048 + t * 4;
  float4 P4 = {p0,p1,p2,p3}; *(float4*)&Pb[base] = P4;
  float4 H4 = {h0,h1,h2,h3}; *(float4*)&he[base] = H4;
}

// K5 (phase B): sequential carry over chunks, 8 blocks x 256 threads, 16-deep prefetch.
// NOTE: hi aliases Pb — no __restrict__ here so program-order load/store is kept.
__global__ __launch_bounds__(256) void k5_carry(
    const float* Pb, const float* he, float* hi)
{
  const int q = blockIdx.x * 256 + threadIdx.x;   // chain id, 0..2047
  float pr[PF], er[PF];
  #pragma unroll
  for (int j = 0; j < PF; j++) {
    pr[j] = Pb[j * 2048 + q];
    er[j] = he[j * 2048 + q];
  }
  float h = 0.f;
  for (int k = 0; k < NCH; k += PF) {
    #pragma unroll
    for (int j = 0; j < PF; j++) {
      int kk = k + j;
      if (kk < NCH) {
        hi[kk * 2048 + q] = h;
        h = fmaf(pr[j], h, er[j]);
        int kn = kk + PF;
        if (kn < NCH) {
          pr[j] = Pb[kn * 2048 + q];
          er[j] = he[kn * 2048 + q];
        }
      }
    }
  }
}

// K6 (phase C): replay scan with carries, fused ys*C + D-skip + z-gate -> y
__global__ __launch_bounds__(512) void k6_scanC(
    const float* __restrict__ dt, const float* __restrict__ xc,
    const float* __restrict__ Bm, const float* __restrict__ Cm,
    const float* __restrict__ zs, const float* __restrict__ Alog,
    const float* __restrict__ Dsk, const float* __restrict__ hi,
    float* __restrict__ y)
{
  __shared__ float sdt[2][2048];
  __shared__ float sxc[2][2048];
  __shared__ float szs[2][2048];
  __shared__ float sBC[2][512];
  const int t = threadIdx.x;
  const int chunk = blockIdx.x;
  const int n0 = chunk * LCH;
  const int srow = t >> 5, scol = (t & 31) * 4;
  const int c = t >> 2, sq = t & 3;
  float4 al = *(const float4*)&Alog[t * 4];
  const float A0 = -__expf(al.x), A1 = -__expf(al.y), A2 = -__expf(al.z), A3 = -__expf(al.w);
  float4 h4 = *(const float4*)&hi[chunk * 2048 + t * 4];
  float h0 = h4.x, h1 = h4.y, h2 = h4.z, h3 = h4.w;
  const float Dc = Dsk[c];

  auto stage = [&](int cb, int buf) {
    int n = n0 + cb * 16 + srow;
    float4 vd = {0,0,0,0}, vx = {0,0,0,0}, vz = {0,0,0,0};
    if (n < N_SEQ) {
      vd = *(const float4*)&dt[n * 128 + scol];
      vx = *(const float4*)&xc[n * 128 + scol];
      vz = *(const float4*)&zs[n * 128 + scol];
    }
    *(float4*)&sdt[buf][srow * 128 + scol] = vd;
    *(float4*)&sxc[buf][srow * 128 + scol] = vx;
    *(float4*)&szs[buf][srow * 128 + scol] = vz;
    if (t < 128) {
      int sel = t >> 6;           // 0: B, 1: C
      int u = t & 63;
      int br = u >> 2, bq = (u & 3) * 4;
      int nb = n0 + cb * 16 + br;
      float4 v = {0,0,0,0};
      if (nb < N_SEQ) v = sel ? *(const float4*)&Cm[nb * 16 + bq]
                              : *(const float4*)&Bm[nb * 16 + bq];
      *(float4*)&sBC[buf][sel * 256 + br * 16 + bq] = v;
    }
  };

  stage(0, 0);
  __syncthreads();
  int cur = 0;
  for (int cb = 0; cb < 4; cb++) {
    if (cb + 1 < 4) stage(cb + 1, cur ^ 1);
    #pragma unroll
    for (int rl = 0; rl < 16; rl++) {
      float dtv = sdt[cur][rl * 128 + c];
      float xv  = sxc[cur][rl * 128 + c];
      float zv  = szs[cur][rl * 128 + c];
      float4 Bv = *(const float4*)&sBC[cur][rl * 16 + sq * 4];
      float4 Cv = *(const float4*)&sBC[cur][256 + rl * 16 + sq * 4];
      float bs = dtv * xv;
      float e0 = __expf(dtv*A0), e1 = __expf(dtv*A1), e2 = __expf(dtv*A2), e3 = __expf(dtv*A3);
      h0 = e0*h0 + bs*Bv.x; h1 = e1*h1 + bs*Bv.y; h2 = e2*h2 + bs*Bv.z; h3 = e3*h3 + bs*Bv.w;
      float part = h0*Cv.x + h1*Cv.y + h2*Cv.z + h3*Cv.w;
      part += __shfl_xor(part, 1, 64);
      part += __shfl_xor(part, 2, 64);
      int n = n0 + cb * 16 + rl;
      if (sq == 0 && n < N_SEQ) y[n * 128 + c] = (part + Dc * xv) * zv;
    }
    __syncthreads();
    cur ^= 1;
  }
}

// K6b: feat = y @ out_proj_w.T + feature ; es[n]=exp(logit), per-block sums   [512 threads]
__global__ __launch_bounds__(512) void k6b_out_attn(
    const float* __restrict__ y, const float* __restrict__ ow,
    const float* __restrict__ featg, const float* __restrict__ aw1,
    const float* __restrict__ ab1, const float* __restrict__ aw2,
    const float* __restrict__ ab2, float* __restrict__ es,
    float* __restrict__ absb)
{
  __shared__ float sm[8448 + 8704 + 1088 + 512];
  float* yl  = sm;               // [64][132]
  float* wo  = sm + 8448;        // [128][68], wo[k*68+f] = ow[f*128+k]
  float* aw  = wo + 8704;        // [16][68]
  float* prt = aw + 1088;        // [8][64]
  const int tid = threadIdx.x;
  const int base = blockIdx.x * 64;
  for (int idx = tid; idx < 64 * 128; idx += 512) {
    int r = idx >> 7, k = idx & 127;
    int n = base + r;
    yl[r * 132 + k] = (n < N_SEQ) ? y[n * 128 + k] : 0.f;
  }
  for (int idx = tid; idx < 64 * 128; idx += 512) {
    int f = idx >> 7, k = idx & 127;
    wo[k * 68 + f] = ow[idx];
  }
  for (int idx = tid; idx < 16 * 64; idx += 512) {
    int j = idx >> 6, f = idx & 63;
    aw[j * 68 + f] = aw1[idx];
  }
  __syncthreads();
  const int fg = tid & 15;
  const int rb = tid >> 4;       // rows rb, rb+32
  float acc[2][4];
  #pragma unroll
  for (int i = 0; i < 2; i++) {
    int n = base + rb + 32 * i;
    if (n < N_SEQ) {
      float4 fv = *(const float4*)&featg[n * 64 + fg * 4];
      acc[i][0]=fv.x; acc[i][1]=fv.y; acc[i][2]=fv.z; acc[i][3]=fv.w;
    } else { acc[i][0]=0; acc[i][1]=0; acc[i][2]=0; acc[i][3]=0; }
  }
  #pragma unroll 4
  for (int k = 0; k < 128; k += 4) {
    float4 y0 = *(const float4*)&yl[(rb +  0) * 132 + k];
    float4 y1 = *(const float4*)&yl[(rb + 32) * 132 + k];
    float4 w0 = *(const float4*)&wo[(k + 0) * 68 + fg * 4];
    float4 w1 = *(const float4*)&wo[(k + 1) * 68 + fg * 4];
    float4 w2 = *(const float4*)&wo[(k + 2) * 68 + fg * 4];
    float4 w3 = *(const float4*)&wo[(k + 3) * 68 + fg * 4];
    acc[0][0] += y0.x*w0.x + y0.y*w1.x + y0.z*w2.x + y0.w*w3.x;
    acc[0][1] += y0.x*w0.y + y0.y*w1.y + y0.z*w2.y + y0.w*w3.y;
    acc[0][2] += y0.x*w0.z + y0.y*w1.z + y0.z*w2.z + y0.w*w3.z;
    acc[0][3] += y0.x*w0.w + y0.y*w1.w + y0.z*w2.w + y0.w*w3.w;
    acc[1][0] += y1.x*w0.x + y1.y*w1.x + y1.z*w2.x + y1.w*w3.x;
    acc[1][1] += y1.x*w0.y + y1.y*w1.y + y1.z*w2.y + y1.w*w3.y;
    acc[1][2] += y1.x*w0.z + y1.y*w1.z + y1.z*w2.z + y1.w*w3.z;
    acc[1][3] += y1.x*w0.w + y1.y*w1.w + y1.z*w2.w + y1.w*w3.w;
  }
  __syncthreads();  // all yl reads done before aliasing as feat storage
  float* flds = sm;  // [64][68]
  #pragma unroll
  for (int i = 0; i < 2; i++) {
    int r = rb + 32 * i;
    float4 o = {acc[i][0], acc[i][1], acc[i][2], acc[i][3]};
    *(float4*)&flds[r * 68 + fg * 4] = o;
  }
  __syncthreads();
  const int r = tid & 63, jg = tid >> 6;   // jg 0..7
  float psum = 0.f;
  #pragma unroll
  for (int jj = 0; jj < 2; jj++) {
    int j = jg * 2 + jj;
    float d = ab1[j];
    #pragma unroll
    for (int k = 0; k < 64; k += 4) {
      float4 fv = *(const float4*)&flds[r * 68 + k];
      float4 wv = *(const float4*)&aw[j * 68 + k];
      d += DOT4(fv, wv);
    }
    psum += tanhf(d) * aw2[j];
  }
  prt[jg * 64 + r] = psum;
  __syncthreads();
  if (tid < 64) {
    int n = base + tid;
    float s = ab2[0];
    #pragma unroll
    for (int g = 0; g < 8; g++) s += prt[g * 64 + tid];
    float e = 0.f;
    if (n < N_SEQ) { e = __expf(s); es[n] = e; }
    #pragma unroll
    for (int off = 32; off > 0; off >>= 1) e += __shfl_down(e, off, 64);
    if (tid == 0) absb[blockIdx.x] = e;
  }
}

// K7b: each block sums absb itself -> inv; writes A_soft and per-block partial M
__global__ __launch_bounds__(256) void k7b_weighted(
    const float* __restrict__ es, const float* __restrict__ featg,
    const float* __restrict__ absb, float* __restrict__ out, float* __restrict__ Mp)
{
  __shared__ float ssum[256];
  __shared__ float prt[4 * 64];
  const int tid = threadIdx.x;
  const int base = blockIdx.x * 256;
  float s = 0.f;
  for (int i = tid; i < NCH; i += 256) s += absb[i];
  ssum[tid] = s; __syncthreads();
  for (int st = 128; st > 0; st >>= 1) { if (tid < st) ssum[tid] += ssum[tid + st]; __syncthreads(); }
  const float inv = 1.f / ssum[0];
  const int f = tid & 63, g = tid >> 6;
  float acc = 0.f;
  for (int rr = g; rr < 256; rr += 4) {
    int n = base + rr;
    if (n < N_SEQ) acc += es[n] * inv * featg[n * 64 + f];
  }
  prt[g * 64 + f] = acc;
  int n = base + tid;
  if (n < N_SEQ) out[64 + n] = es[n] * inv;
  __syncthreads();
  if (tid < 64) Mp[blockIdx.x * 64 + tid] = prt[tid] + prt[64 + tid] + prt[128 + tid] + prt[192 + tid];
}

// K7c: M = sum of partials
__global__ __launch_bounds__(64) void k7c_reduceM(
    const float* __restrict__ Mp, float* __restrict__ out)
{
  const int f = threadIdx.x;
  float s = 0.f;
  for (int b = 0; b < NB7; b++) s += Mp[b * 64 + f];
  out[f] = s;
}

extern "C" void kernel_launch(void* const* d_in, const int* in_sizes, int n_in,
                              void* d_out, int out_size, void* d_ws, size_t ws_size,
                              hipStream_t stream)
{
  const float* xp   = (const float*)d_in[0];
  const float* W1   = (const float*)d_in[1];
  const float* b1   = (const float*)d_in[2];
  const float* ipw  = (const float*)d_in[3];
  const float* cw   = (const float*)d_in[4];
  const float* cb   = (const float*)d_in[5];
  const float* xpw  = (const float*)d_in[6];
  const float* dtw  = (const float*)d_in[7];
  const float* dtb  = (const float*)d_in[8];
  const float* Alog = (const float*)d_in[9];
  const float* Dsk  = (const float*)d_in[10];
  const float* ow   = (const float*)d_in[11];
  const float* aw1  = (const float*)d_in[12];
  const float* ab1  = (const float*)d_in[13];
  const float* aw2  = (const float*)d_in[14];
  const float* ab2  = (const float*)d_in[15];

  float* ws = (float*)d_ws;
  float* feature = ws;                       // 1,280,000
  float* xz_x = feature + 1280000;           // 2,560,000 (y alias after k3)
  float* zs   = xz_x + 2560000;              // 2,560,000
  float* xc   = zs + 2560000;                // 2,560,000
  float* dt   = xc + 2560000;                // 2,560,000
  float* Bm   = dt + 2560000;                // 320,000
  float* Cm   = Bm + 320000;                 // 320,000
  float* Pb   = Cm + 320000;                 // 641,024 (hi alias after k5)
  float* he   = Pb + 641024;                 // 641,024
  float* esb  = he + 641024;                 // 20,000 (exp of logits)
  float* absb = esb + 20000;                 // 320 (per-block exp sums)
  float* Mp   = absb + 320;                  // 5,056
  ushort* whi = (ushort*)(Mp + 5056);        // 65,536 ushorts
  ushort* wlo = whi + 65536;                 // 65,536 ushorts
  float* hi   = Pb;
  float* yv   = xz_x;
  float* out  = (float*)d_out;

  k0_convW<<<256, 256, 0, stream>>>(W1, whi, wlo);
  k1_fused<<<625, 512, 0, stream>>>(xp, whi, wlo, b1, feature);
  k2_inproj<<<dim3(313, 4), 256, 0, stream>>>(feature, ipw, xz_x, zs);
  k3_conv_proj<<<417, 512, 0, stream>>>(xz_x, cw, cb, xpw, dtw, dtb, xc, dt, Bm, Cm);
  k4_scanA<<<NCH, 512, 0, stream>>>(dt, xc, Bm, Alog, Pb, he);
  k5_carry<<<8, 256, 0, stream>>>(Pb, he, hi);
  k6_scanC<<<NCH, 512, 0, stream>>>(dt, xc, Bm, Cm, zs, Alog, Dsk, hi, yv);
  k6b_out_attn<<<313, 512, 0, stream>>>(yv, ow, feature, aw1, ab1, aw2, ab2, esb, absb);
  k7b_weighted<<<NB7, 256, 0, stream>>>(esb, feature, absb, out, Mp);
  k7c_reduceM<<<1, 64, 0, stream>>>(Mp, out);
}